// Round 1
// baseline (2107.310 us; speedup 1.0000x reference)
//
#include <hip/hip_runtime.h>
#include <math.h>

#define NN 50000
#define NE 800000
#define DNODE 128
#define DEDGE 64
#define HD 96

__device__ __forceinline__ float lrelu(float x){ return x > 0.f ? x : 0.2f*x; }

// ---- CSR build ----------------------------------------------------------
__global__ void k_count(const int* __restrict__ dst, int* __restrict__ cnt){
  int e = blockIdx.x*256 + threadIdx.x;
  if (e < NE) atomicAdd(&cnt[dst[e]], 1);
}

__global__ __launch_bounds__(1024) void k_scan(const int* __restrict__ cnt,
                                               int* __restrict__ rowptr){
  __shared__ int sm[1024];
  __shared__ int run_s;
  int t = threadIdx.x;
  if (t == 0) run_s = 0;
  __syncthreads();
  const int nch = (NN + 1023)/1024;
  for (int c=0;c<nch;c++){
    int i = c*1024 + t;
    int v = (i < NN) ? cnt[i] : 0;
    sm[t] = v;
    __syncthreads();
    for (int off=1; off<1024; off<<=1){
      int add = (t >= off) ? sm[t-off] : 0;
      __syncthreads();
      sm[t] += add;
      __syncthreads();
    }
    if (i < NN) rowptr[i] = run_s + sm[t] - v;   // exclusive prefix
    int total = sm[1023];
    __syncthreads();
    if (t == 0) run_s += total;
    __syncthreads();
  }
  if (t == 0) rowptr[NN] = run_s;
}

__global__ void k_fill(const int* __restrict__ src, const int* __restrict__ dst,
                       const int* __restrict__ rowptr, int* __restrict__ fillc,
                       int* __restrict__ perm, int* __restrict__ src_s){
  int e = blockIdx.x*256 + threadIdx.x;
  if (e >= NE) return;
  int d = dst[e];
  int pos = rowptr[d] + atomicAdd(&fillc[d], 1);
  perm[pos]  = e;
  src_s[pos] = src[e];
}

// ---- small helpers ------------------------------------------------------
// v[k] = sum_j We[k,j] * ae[j]
__global__ void k_vec(const float* __restrict__ We, const float* __restrict__ ae,
                      float* __restrict__ v, int K){
  int k = threadIdx.x;
  if (k < K){
    float s = 0.f;
    for (int j=0;j<HD;j++) s += We[k*HD + j]*ae[j];
    v[k] = s;
  }
}

// elr[e] = dot(Ein[e,:], v)
__global__ void k_elr(const float* __restrict__ Ein, const float* __restrict__ v,
                      float* __restrict__ elr, int K){
  int e = blockIdx.x*256 + threadIdx.x;
  if (e >= NE) return;
  const float4* row = (const float4*)(Ein + (size_t)e*K);
  float s = 0.f;
  for (int k=0;k<K/4;k++){
    float4 a = row[k];
    float4 b = ((const float4*)v)[k];
    s += a.x*b.x + a.y*b.y + a.z*b.z + a.w*b.w;
  }
  elr[e] = s;
}

// slp[n] = segsum(elr, dst)[n] / max(cnt,1)
__global__ void k_sloop(const int* __restrict__ rowptr, const int* __restrict__ perm,
                        const float* __restrict__ elr, float* __restrict__ slp){
  int n = blockIdx.x*256 + threadIdx.x;
  if (n >= NN) return;
  int b = rowptr[n], e = rowptr[n+1];
  float s = 0.f;
  for (int i=b;i<e;i++) s += elr[perm[i]];
  slp[n] = s / fmaxf((float)(e-b), 1.f);
}

// hs[n] = h[n,:]@va ; hd[n] = h[n,:]@vb
__global__ void k_dots(const float* __restrict__ h, const float* __restrict__ va,
                       const float* __restrict__ vb, float* __restrict__ hs,
                       float* __restrict__ hd){
  int n = blockIdx.x*256 + threadIdx.x;
  if (n >= NN) return;
  const float4* row = (const float4*)(h + (size_t)n*HD);
  float s1=0.f, s2=0.f;
  #pragma unroll
  for (int k=0;k<HD/4;k++){
    float4 a = row[k];
    float4 u = ((const float4*)va)[k];
    float4 w = ((const float4*)vb)[k];
    s1 += a.x*u.x + a.y*u.y + a.z*u.z + a.w*u.w;
    s2 += a.x*w.x + a.y*w.y + a.z*w.z + a.w*w.w;
  }
  hs[n]=s1; hd[n]=s2;
}

// ---- GEMMs --------------------------------------------------------------
// Y[M,96] = X[M,K] @ W[K,96] (+bias). block: 32 rows x 8 col-groups of 12.
__global__ __launch_bounds__(256) void k_nodegemm(const float* __restrict__ X,
    const float* __restrict__ W, const float* __restrict__ bias,
    float* __restrict__ Y, int M, int K){
  __shared__ float Wl[DNODE*HD];
  for (int idx=threadIdx.x; idx<K*HD; idx+=256) Wl[idx] = W[idx];
  __syncthreads();
  int r  = threadIdx.x >> 3;
  int c0 = (threadIdx.x & 7)*12;
  int row = blockIdx.x*32 + r;
  if (row >= M) return;
  float acc[12];
  #pragma unroll
  for (int j=0;j<12;j++) acc[j]=0.f;
  const float* xr = X + (size_t)row*K;
  for (int k=0;k<K;k+=4){
    float4 xv = *(const float4*)(xr + k);
    float xs[4] = {xv.x, xv.y, xv.z, xv.w};
    #pragma unroll
    for (int kk=0;kk<4;kk++){
      const float* wr = Wl + (k+kk)*HD + c0;
      #pragma unroll
      for (int j=0;j<12;j++) acc[j] += xs[kk]*wr[j];
    }
  }
  float* yr = Y + (size_t)row*HD + c0;
  if (bias){
    #pragma unroll
    for (int j=0;j<12;j++) yr[j] = acc[j] + bias[c0+j];
  } else {
    #pragma unroll
    for (int j=0;j<12;j++) yr[j] = acc[j];
  }
}

// Out[e,:] = Ein[e,:]@W + A[src[e],:] + B[dst[e],:] + bias   (in-place safe)
__global__ __launch_bounds__(256) void k_edgegemm(const float* __restrict__ Ein,
    const float* __restrict__ W, int K,
    const float* __restrict__ A, const float* __restrict__ B,
    const int* __restrict__ src, const int* __restrict__ dst,
    const float* __restrict__ bias, float* __restrict__ Out){
  __shared__ float Wl[HD*HD];
  for (int idx=threadIdx.x; idx<K*HD; idx+=256) Wl[idx] = W[idx];
  __syncthreads();
  int r  = threadIdx.x >> 3;
  int c0 = (threadIdx.x & 7)*12;
  int e = blockIdx.x*32 + r;
  bool valid = e < NE;
  float acc[12];
  #pragma unroll
  for (int j=0;j<12;j++) acc[j]=0.f;
  if (valid){
    const float* er = Ein + (size_t)e*K;
    for (int k=0;k<K;k+=4){
      float4 xv = *(const float4*)(er + k);
      float xs[4]={xv.x,xv.y,xv.z,xv.w};
      #pragma unroll
      for (int kk=0;kk<4;kk++){
        const float* wr = Wl + (k+kk)*HD + c0;
        #pragma unroll
        for (int j=0;j<12;j++) acc[j] += xs[kk]*wr[j];
      }
    }
  }
  __syncthreads();   // in-place safety: all reads of this tile done before stores
  if (!valid) return;
  int s = src[e], d = dst[e];
  const float* Ar = A + (size_t)s*HD + c0;
  const float* Br = B + (size_t)d*HD + c0;
  float* orow = Out + (size_t)e*HD + c0;
  #pragma unroll
  for (int j=0;j<12;j++) orow[j] = acc[j] + Ar[j] + Br[j] + bias[c0+j];
}

// ---- GAT softmax + aggregation (one wave per node) ----------------------
__global__ __launch_bounds__(256) void k_gat(const int* __restrict__ rowptr,
    const int* __restrict__ src_s, const int* __restrict__ perm,
    const float* __restrict__ hs, const float* __restrict__ hd,
    const float* __restrict__ elr, const float* __restrict__ slp,
    const float* __restrict__ h, const float* __restrict__ bias,
    float* __restrict__ Out){
  int lane = threadIdx.x & 63;
  int n = blockIdx.x*4 + (threadIdx.x >> 6);
  if (n >= NN) return;
  int beg = rowptr[n], end = rowptr[n+1];
  float hdn = hd[n];
  float selfL = lrelu(hs[n] + hdn + slp[n]);
  float mx = selfL;
  for (int i = beg + lane; i < end; i += 64)
    mx = fmaxf(mx, lrelu(hs[src_s[i]] + hdn + elr[perm[i]]));
  #pragma unroll
  for (int o=32;o>0;o>>=1) mx = fmaxf(mx, __shfl_xor(mx, o, 64));
  float acc0 = 0.f, acc1 = 0.f, denom = 0.f;
  for (int i = beg; i < end; ++i){
    int s = src_s[i];
    float p = __expf(lrelu(hs[s] + hdn + elr[perm[i]]) - mx);
    denom += p;
    acc0 += p * h[(size_t)s*HD + lane];
    if (lane < 32) acc1 += p * h[(size_t)s*HD + 64 + lane];
  }
  float ps = __expf(selfL - mx);
  denom += ps;
  acc0 += ps * h[(size_t)n*HD + lane];
  if (lane < 32) acc1 += ps * h[(size_t)n*HD + 64 + lane];
  float inv = 1.f/denom;
  Out[(size_t)n*HD + lane] = acc0*inv + bias[lane];
  if (lane < 32) Out[(size_t)n*HD + 64 + lane] = acc1*inv + bias[64+lane];
}

// ---- driver -------------------------------------------------------------
extern "C" void kernel_launch(void* const* d_in, const int* in_sizes, int n_in,
                              void* d_out, int out_size, void* d_ws, size_t ws_size,
                              hipStream_t stream){
  const float* x   = (const float*)d_in[0];
  const int*   ei  = (const int*)d_in[1];
  const float* ea  = (const float*)d_in[2];
  const float* w0  = (const float*)d_in[3];
  const float* we0 = (const float*)d_in[4];
  const float* as0 = (const float*)d_in[5];
  const float* ad0 = (const float*)d_in[6];
  const float* ae0 = (const float*)d_in[7];
  const float* b0  = (const float*)d_in[8];
  const float* ew0 = (const float*)d_in[9];
  const float* eb0 = (const float*)d_in[10];
  const float* w1  = (const float*)d_in[11];
  const float* we1 = (const float*)d_in[12];
  const float* as1 = (const float*)d_in[13];
  const float* ad1 = (const float*)d_in[14];
  const float* ae1 = (const float*)d_in[15];
  const float* b1  = (const float*)d_in[16];
  const float* ew1 = (const float*)d_in[17];
  const float* eb1 = (const float*)d_in[18];

  const int* srcp = ei;
  const int* dstp = ei + NE;

  char* ws = (char*)d_ws;
  size_t off = 0;
  auto carve = [&](size_t bytes)->char*{
    char* p = ws + off; off += (bytes + 255) & ~(size_t)255; return p;
  };
  int*   rowptr = (int*)carve(4ull*(NN+1));
  int*   fillc  = (int*)carve(4ull*NN);
  int*   perm   = (int*)carve(4ull*NE);
  int*   src_s  = (int*)carve(4ull*NE);
  float* hbuf   = (float*)carve(4ull*NN*HD);
  float* x0     = (float*)carve(4ull*NN*HD);
  float* Ab     = (float*)carve(4ull*NN*HD);
  float* Bb     = (float*)carve(4ull*NN*HD);
  float* hsb    = (float*)carve(4ull*NN);
  float* hdb    = (float*)carve(4ull*NN);
  float* slp    = (float*)carve(4ull*NN);
  float* elr    = (float*)carve(4ull*NE);
  float* vsm    = (float*)carve(4ull*128);
  (void)ws_size; (void)in_sizes; (void)n_in; (void)out_size;

  float* xout  = (float*)d_out;                    // [NN,HD]
  float* eaout = (float*)d_out + (size_t)NN*HD;    // [NE,HD]

  const int EB = (NE + 255)/256;
  const int NB = (NN + 255)/256;

  // CSR (by dst), built fresh every launch
  hipMemsetAsync(fillc, 0, 4ull*NN, stream);
  k_count<<<EB, 256, 0, stream>>>(dstp, fillc);
  k_scan<<<1, 1024, 0, stream>>>(fillc, rowptr);
  hipMemsetAsync(fillc, 0, 4ull*NN, stream);
  k_fill<<<EB, 256, 0, stream>>>(srcp, dstp, rowptr, fillc, perm, src_s);

  // ---- layer 0 ----
  k_vec<<<1, 128, 0, stream>>>(we0, ae0, vsm, DEDGE);
  k_elr<<<EB, 256, 0, stream>>>(ea, vsm, elr, DEDGE);
  k_sloop<<<NB, 256, 0, stream>>>(rowptr, perm, elr, slp);
  k_nodegemm<<<(NN+31)/32, 256, 0, stream>>>(x, w0, nullptr, hbuf, NN, DNODE);
  k_dots<<<NB, 256, 0, stream>>>(hbuf, as0, ad0, hsb, hdb);
  k_gat<<<(NN+3)/4, 256, 0, stream>>>(rowptr, src_s, perm, hsb, hdb, elr, slp, hbuf, b0, x0);

  // edge update 0: eaout = ea@ew0[192:] + (x0@ew0[0:96])[src] + (x0@ew0[96:192])[dst] + eb0
  k_nodegemm<<<(NN+31)/32, 256, 0, stream>>>(x0, ew0,           nullptr, Ab, NN, HD);
  k_nodegemm<<<(NN+31)/32, 256, 0, stream>>>(x0, ew0 + 96*HD,   nullptr, Bb, NN, HD);
  k_edgegemm<<<NE/32, 256, 0, stream>>>(ea, ew0 + 192*HD, DEDGE, Ab, Bb, srcp, dstp, eb0, eaout);

  // ---- layer 1 ----
  k_vec<<<1, 128, 0, stream>>>(we1, ae1, vsm, HD);
  k_elr<<<EB, 256, 0, stream>>>(eaout, vsm, elr, HD);
  k_sloop<<<NB, 256, 0, stream>>>(rowptr, perm, elr, slp);
  k_nodegemm<<<(NN+31)/32, 256, 0, stream>>>(x0, w1, nullptr, hbuf, NN, HD);
  k_dots<<<NB, 256, 0, stream>>>(hbuf, as1, ad1, hsb, hdb);
  k_gat<<<(NN+3)/4, 256, 0, stream>>>(rowptr, src_s, perm, hsb, hdb, elr, slp, hbuf, b1, xout);

  // edge update 1 (in-place on eaout)
  k_nodegemm<<<(NN+31)/32, 256, 0, stream>>>(xout, ew1,         nullptr, Ab, NN, HD);
  k_nodegemm<<<(NN+31)/32, 256, 0, stream>>>(xout, ew1 + 96*HD, nullptr, Bb, NN, HD);
  k_edgegemm<<<NE/32, 256, 0, stream>>>(eaout, ew1 + 192*HD, HD, Ab, Bb, srcp, dstp, eb1, eaout);
}